// Round 1
// baseline (3625.033 us; speedup 1.0000x reference)
//
#include <hip/hip_runtime.h>

// GCN 3-layer: N=50000, E=800000, dims 128->128->128->64, fp32.
// Pipeline per layer: gemm (LDS-tiled fp32) -> zero agg -> edge scatter
// (atomicAdd) -> combine (agg + xw*dinv^2 + b [+relu]).
// deg/dinv/norm computed once, reused across layers.

#define C_IN 128
#define C_HID 128
#define C_OUT 64

__global__ void deg_kernel(const int* __restrict__ dst, int E, float* __restrict__ deg) {
    int e = blockIdx.x * blockDim.x + threadIdx.x;
    if (e < E) atomicAdd(&deg[dst[e]], 1.0f);
}

__global__ void dinv_kernel(float* __restrict__ deg, int n) {
    int i = blockIdx.x * blockDim.x + threadIdx.x;
    if (i < n) deg[i] = rsqrtf(deg[i] + 1.0f);
}

__global__ void norm_kernel(const int* __restrict__ src, const int* __restrict__ dst, int E,
                            const float* __restrict__ dinv, float* __restrict__ norm) {
    int e = blockIdx.x * blockDim.x + threadIdx.x;
    if (e < E) norm[e] = dinv[src[e]] * dinv[dst[e]];
}

// X[n,128] @ W[128,FOUT] -> Y[n,FOUT].  Tile: 64 rows x 64 cols, K=128 staged in LDS.
template <int FOUT>
__global__ __launch_bounds__(256, 2) void gemm_k128(const float* __restrict__ X,
                                                    const float* __restrict__ W,
                                                    float* __restrict__ Y, int n) {
    constexpr int K = 128;
    constexpr int CT = 64;        // col tile
    constexpr int MT = 64;        // row tile
    constexpr int NQ = CT / 4;    // 16 col-quads
    constexpr int RPT = 4;        // rows per thread
    __shared__ float Ws[K][CT];       // 32 KB
    __shared__ float Xs[MT][K + 4];   // 33.8 KB (pad to break bank aliasing)

    int tid = threadIdx.x;
    int row0 = blockIdx.x * MT;
    int col0 = blockIdx.y * CT;

    // Load W slice [128][CT]
#pragma unroll
    for (int i = 0; i < (K * CT / 4) / 256; ++i) {
        int idx = tid + i * 256;
        int k = idx / (CT / 4);
        int c = idx % (CT / 4);
        *(float4*)&Ws[k][c * 4] = *(const float4*)(W + (size_t)k * FOUT + col0 + c * 4);
    }
    // Load X tile [MT][128]
#pragma unroll
    for (int i = 0; i < (MT * K / 4) / 256; ++i) {
        int idx = tid + i * 256;
        int r = idx / (K / 4);
        int c = idx % (K / 4);
        int gr = row0 + r;
        float4 v = (gr < n) ? *(const float4*)(X + (size_t)gr * K + c * 4)
                            : make_float4(0.f, 0.f, 0.f, 0.f);
        *(float4*)&Xs[r][c * 4] = v;
    }
    __syncthreads();

    int cq = tid % NQ;
    int rg = tid / NQ;   // 0..15
    float acc[RPT][4] = {};

    for (int k4 = 0; k4 < K / 4; ++k4) {
        float xa[RPT][4];
#pragma unroll
        for (int r = 0; r < RPT; ++r) {
            float4 t = *(float4*)&Xs[rg * RPT + r][k4 * 4];
            xa[r][0] = t.x; xa[r][1] = t.y; xa[r][2] = t.z; xa[r][3] = t.w;
        }
#pragma unroll
        for (int kk = 0; kk < 4; ++kk) {
            float4 w = *(float4*)&Ws[k4 * 4 + kk][cq * 4];
#pragma unroll
            for (int r = 0; r < RPT; ++r) {
                acc[r][0] = fmaf(xa[r][kk], w.x, acc[r][0]);
                acc[r][1] = fmaf(xa[r][kk], w.y, acc[r][1]);
                acc[r][2] = fmaf(xa[r][kk], w.z, acc[r][2]);
                acc[r][3] = fmaf(xa[r][kk], w.w, acc[r][3]);
            }
        }
    }
#pragma unroll
    for (int r = 0; r < RPT; ++r) {
        int gr = row0 + rg * RPT + r;
        if (gr < n)
            *(float4*)(Y + (size_t)gr * FOUT + col0 + cq * 4) =
                make_float4(acc[r][0], acc[r][1], acc[r][2], acc[r][3]);
    }
}

// One thread per (edge, 4-float quad): gather xw[src] row, scale, atomicAdd into agg[dst].
template <int F>
__global__ void scatter_kernel(const int* __restrict__ src, const int* __restrict__ dst,
                               const float* __restrict__ norm, const float* __restrict__ xw,
                               float* __restrict__ agg, int E) {
    constexpr int TPE = F / 4;
    int gid = blockIdx.x * blockDim.x + threadIdx.x;
    int e = gid / TPE;
    int q = gid % TPE;
    if (e >= E) return;
    int s = src[e];
    int d = dst[e];
    float nv = norm[e];
    float4 v = ((const float4*)(xw + (size_t)s * F))[q];
    float* out = agg + (size_t)d * F + q * 4;
    atomicAdd(out + 0, v.x * nv);
    atomicAdd(out + 1, v.y * nv);
    atomicAdd(out + 2, v.z * nv);
    atomicAdd(out + 3, v.w * nv);
}

// out = agg + xw * dinv^2 + b  [+ relu]
template <int F, bool RELU>
__global__ void combine_kernel(const float* __restrict__ agg, const float* __restrict__ xw,
                               const float* __restrict__ dinv, const float* __restrict__ b,
                               float* __restrict__ out, int n) {
    int gid = blockIdx.x * blockDim.x + threadIdx.x;
    constexpr int Q = F / 4;
    if (gid >= n * Q) return;
    int i = gid / Q;
    int q = gid % Q;
    float s = dinv[i];
    s = s * s;
    float4 a = ((const float4*)agg)[gid];
    float4 x = ((const float4*)xw)[gid];
    float4 bv = ((const float4*)b)[q];
    float4 o;
    o.x = fmaf(x.x, s, a.x) + bv.x;
    o.y = fmaf(x.y, s, a.y) + bv.y;
    o.z = fmaf(x.z, s, a.z) + bv.z;
    o.w = fmaf(x.w, s, a.w) + bv.w;
    if (RELU) {
        o.x = fmaxf(o.x, 0.f);
        o.y = fmaxf(o.y, 0.f);
        o.z = fmaxf(o.z, 0.f);
        o.w = fmaxf(o.w, 0.f);
    }
    ((float4*)out)[gid] = o;
}

extern "C" void kernel_launch(void* const* d_in, const int* in_sizes, int n_in,
                              void* d_out, int out_size, void* d_ws, size_t ws_size,
                              hipStream_t stream) {
    const float* x  = (const float*)d_in[0];
    const int*   ei = (const int*)d_in[1];
    const float* W1 = (const float*)d_in[2];
    const float* b1 = (const float*)d_in[3];
    const float* W2 = (const float*)d_in[4];
    const float* b2 = (const float*)d_in[5];
    const float* W3 = (const float*)d_in[6];
    const float* b3 = (const float*)d_in[7];
    float* out = (float*)d_out;

    int E = in_sizes[1] / 2;
    int n = in_sizes[0] / C_IN;
    const int* src = ei;
    const int* dst = ei + E;

    float* A    = (float*)d_ws;                 // xw buffer [n][128]
    float* B    = A + (size_t)n * C_HID;        // agg/h buffer [n][128]
    float* dinv = B + (size_t)n * C_HID;        // [n]
    float* nrm  = dinv + n;                     // [E]

    // --- degree / dinv / per-edge norm (once) ---
    hipMemsetAsync(dinv, 0, (size_t)n * sizeof(float), stream);
    deg_kernel<<<(E + 255) / 256, 256, 0, stream>>>(dst, E, dinv);
    dinv_kernel<<<(n + 255) / 256, 256, 0, stream>>>(dinv, n);
    norm_kernel<<<(E + 255) / 256, 256, 0, stream>>>(src, dst, E, dinv, nrm);

    dim3 g128((n + 63) / 64, C_HID / 64);
    dim3 g64((n + 63) / 64, 1);
    int scat128 = (E * (C_HID / 4) + 255) / 256;
    int scat64  = (E * (C_OUT / 4) + 255) / 256;
    int comb128 = (n * (C_HID / 4) + 255) / 256;
    int comb64  = (n * (C_OUT / 4) + 255) / 256;

    // --- layer 1: x @ W1 ---
    gemm_k128<C_HID><<<g128, 256, 0, stream>>>(x, W1, A, n);
    hipMemsetAsync(B, 0, (size_t)n * C_HID * sizeof(float), stream);
    scatter_kernel<C_HID><<<scat128, 256, 0, stream>>>(src, dst, nrm, A, B, E);
    combine_kernel<C_HID, false><<<comb128, 256, 0, stream>>>(B, A, dinv, b1, B, n);

    // --- layer 2: h1 @ W2 ---
    gemm_k128<C_HID><<<g128, 256, 0, stream>>>(B, W2, A, n);
    hipMemsetAsync(B, 0, (size_t)n * C_HID * sizeof(float), stream);
    scatter_kernel<C_HID><<<scat128, 256, 0, stream>>>(src, dst, nrm, A, B, E);
    combine_kernel<C_HID, false><<<comb128, 256, 0, stream>>>(B, A, dinv, b2, B, n);

    // --- layer 3: h2 @ W3 (64 cols) ---
    gemm_k128<C_OUT><<<g64, 256, 0, stream>>>(B, W3, A, n);
    hipMemsetAsync(B, 0, (size_t)n * C_OUT * sizeof(float), stream);
    scatter_kernel<C_OUT><<<scat64, 256, 0, stream>>>(src, dst, nrm, A, B, E);
    combine_kernel<C_OUT, true><<<comb64, 256, 0, stream>>>(B, A, dinv, b3, out, n);
}

// Round 2
// 438.880 us; speedup vs baseline: 8.2597x; 8.2597x over previous
//
#include <hip/hip_runtime.h>

// GCN 3-layer: N=50000, E=800000, dims 128->128->128->64, fp32.
// Strategy: build CSR (counting sort by dst) ONCE per launch, then per layer:
//   gemm (LDS-tiled fp32)  ->  per-node wave gather-aggregate (fused self-loop,
//   bias, relu).  No atomics in the hot path.

#define C_IN 128
#define C_HID 128
#define C_OUT 64
#define SCAN_T 256
#define SCAN_ELEMS (SCAN_T * 4)

// ---------------- CSR build ----------------

__global__ void count_deg_kernel(const int* __restrict__ dst, int E, int* __restrict__ degi) {
    int e = blockIdx.x * blockDim.x + threadIdx.x;
    if (e < E) atomicAdd(&degi[dst[e]], 1);
}

__global__ void dinv_kernel(const int* __restrict__ degi, float* __restrict__ dinv, int n) {
    int i = blockIdx.x * blockDim.x + threadIdx.x;
    if (i < n) dinv[i] = rsqrtf((float)degi[i] + 1.0f);
}

// exclusive scan, pass 1: per-block (1024 elems) scan + block totals
__global__ void scan1_kernel(const int* __restrict__ degi, int n,
                             int* __restrict__ excl, int* __restrict__ partials) {
    __shared__ int lds[SCAN_T];
    int tid = threadIdx.x;
    int base = blockIdx.x * SCAN_ELEMS + tid * 4;
    int a0 = (base + 0 < n) ? degi[base + 0] : 0;
    int a1 = (base + 1 < n) ? degi[base + 1] : 0;
    int a2 = (base + 2 < n) ? degi[base + 2] : 0;
    int a3 = (base + 3 < n) ? degi[base + 3] : 0;
    int t = a0 + a1 + a2 + a3;
    lds[tid] = t;
    __syncthreads();
    for (int off = 1; off < SCAN_T; off <<= 1) {
        int v = (tid >= off) ? lds[tid - off] : 0;
        __syncthreads();
        lds[tid] += v;
        __syncthreads();
    }
    int incl = lds[tid];
    int ex = incl - t;
    if (base + 0 < n) excl[base + 0] = ex;
    if (base + 1 < n) excl[base + 1] = ex + a0;
    if (base + 2 < n) excl[base + 2] = ex + a0 + a1;
    if (base + 3 < n) excl[base + 3] = ex + a0 + a1 + a2;
    if (tid == SCAN_T - 1) partials[blockIdx.x] = incl;
}

// pass 2: serial exclusive scan of ~49 block totals (negligible)
__global__ void scan2_kernel(int* __restrict__ partials, int nb) {
    if (threadIdx.x == 0 && blockIdx.x == 0) {
        int run = 0;
        for (int i = 0; i < nb; ++i) { int v = partials[i]; partials[i] = run; run += v; }
    }
}

// pass 3: add block offsets; set rowptr[n] = E
__global__ void scan3_kernel(int* __restrict__ excl, const int* __restrict__ partials,
                             int n, int E) {
    int gid = blockIdx.x * blockDim.x + threadIdx.x;
    if (gid < n) excl[gid] += partials[gid / SCAN_ELEMS];
    if (gid == 0) excl[n] = E;
}

__global__ void fill_csr_kernel(const int* __restrict__ src, const int* __restrict__ dst, int E,
                                const float* __restrict__ dinv, const int* __restrict__ rowptr,
                                int* __restrict__ cursor, int* __restrict__ csr_src,
                                float* __restrict__ csr_nrm) {
    int e = blockIdx.x * blockDim.x + threadIdx.x;
    if (e >= E) return;
    int s = src[e], d = dst[e];
    int pos = rowptr[d] + atomicAdd(&cursor[d], 1);
    csr_src[pos] = s;
    csr_nrm[pos] = dinv[s] * dinv[d];
}

// ---------------- GEMM: X[n,128] @ W[128,FOUT] -> Y[n,FOUT] ----------------
template <int FOUT>
__global__ __launch_bounds__(256, 2) void gemm_k128(const float* __restrict__ X,
                                                    const float* __restrict__ W,
                                                    float* __restrict__ Y, int n) {
    constexpr int K = 128;
    constexpr int CT = 64;
    constexpr int MT = 64;
    constexpr int NQ = CT / 4;
    constexpr int RPT = 4;
    __shared__ float Ws[K][CT];
    __shared__ float Xs[MT][K + 4];

    int tid = threadIdx.x;
    int row0 = blockIdx.x * MT;
    int col0 = blockIdx.y * CT;

#pragma unroll
    for (int i = 0; i < (K * CT / 4) / 256; ++i) {
        int idx = tid + i * 256;
        int k = idx / (CT / 4);
        int c = idx % (CT / 4);
        *(float4*)&Ws[k][c * 4] = *(const float4*)(W + (size_t)k * FOUT + col0 + c * 4);
    }
#pragma unroll
    for (int i = 0; i < (MT * K / 4) / 256; ++i) {
        int idx = tid + i * 256;
        int r = idx / (K / 4);
        int c = idx % (K / 4);
        int gr = row0 + r;
        float4 v = (gr < n) ? *(const float4*)(X + (size_t)gr * K + c * 4)
                            : make_float4(0.f, 0.f, 0.f, 0.f);
        *(float4*)&Xs[r][c * 4] = v;
    }
    __syncthreads();

    int cq = tid % NQ;
    int rg = tid / NQ;
    float acc[RPT][4] = {};

    for (int k4 = 0; k4 < K / 4; ++k4) {
        float xa[RPT][4];
#pragma unroll
        for (int r = 0; r < RPT; ++r) {
            float4 t = *(float4*)&Xs[rg * RPT + r][k4 * 4];
            xa[r][0] = t.x; xa[r][1] = t.y; xa[r][2] = t.z; xa[r][3] = t.w;
        }
#pragma unroll
        for (int kk = 0; kk < 4; ++kk) {
            float4 w = *(float4*)&Ws[k4 * 4 + kk][cq * 4];
#pragma unroll
            for (int r = 0; r < RPT; ++r) {
                acc[r][0] = fmaf(xa[r][kk], w.x, acc[r][0]);
                acc[r][1] = fmaf(xa[r][kk], w.y, acc[r][1]);
                acc[r][2] = fmaf(xa[r][kk], w.z, acc[r][2]);
                acc[r][3] = fmaf(xa[r][kk], w.w, acc[r][3]);
            }
        }
    }
#pragma unroll
    for (int r = 0; r < RPT; ++r) {
        int gr = row0 + rg * RPT + r;
        if (gr < n)
            *(float4*)(Y + (size_t)gr * FOUT + col0 + cq * 4) =
                make_float4(acc[r][0], acc[r][1], acc[r][2], acc[r][3]);
    }
}

// ---------------- fused aggregate: out = sum_j nrm*xw[src] + xw*dinv^2 + b [+relu] ---------
// one wave per node; 64 lanes hold the F-dim row (float2 per lane for F=128).
template <int F, bool RELU>
__global__ __launch_bounds__(256) void agg_kernel(const int* __restrict__ rowptr,
                                                  const int* __restrict__ csr_src,
                                                  const float* __restrict__ csr_nrm,
                                                  const float* __restrict__ xw,
                                                  const float* __restrict__ dinv,
                                                  const float* __restrict__ bias,
                                                  float* __restrict__ out, int n) {
    int wave = threadIdx.x >> 6;
    int lane = threadIdx.x & 63;
    int i = blockIdx.x * 4 + wave;
    if (i >= n) return;
    float di = dinv[i];
    float d2 = di * di;
    int j = rowptr[i];
    int end = rowptr[i + 1];

    if constexpr (F == 128) {
        float2 x0 = ((const float2*)(xw + (size_t)i * F))[lane];
        float a0 = x0.x * d2, a1 = x0.y * d2;
        for (; j + 1 < end; j += 2) {
            int s0 = csr_src[j], s1 = csr_src[j + 1];
            float n0 = csr_nrm[j], n1 = csr_nrm[j + 1];
            float2 v0 = ((const float2*)(xw + (size_t)s0 * F))[lane];
            float2 v1 = ((const float2*)(xw + (size_t)s1 * F))[lane];
            a0 = fmaf(v0.x, n0, a0); a1 = fmaf(v0.y, n0, a1);
            a0 = fmaf(v1.x, n1, a0); a1 = fmaf(v1.y, n1, a1);
        }
        if (j < end) {
            int s0 = csr_src[j];
            float n0 = csr_nrm[j];
            float2 v0 = ((const float2*)(xw + (size_t)s0 * F))[lane];
            a0 = fmaf(v0.x, n0, a0); a1 = fmaf(v0.y, n0, a1);
        }
        float2 bv = ((const float2*)bias)[lane];
        float2 o;
        o.x = a0 + bv.x; o.y = a1 + bv.y;
        if (RELU) { o.x = fmaxf(o.x, 0.f); o.y = fmaxf(o.y, 0.f); }
        ((float2*)(out + (size_t)i * F))[lane] = o;
    } else {  // F == 64, one float per lane
        float a0 = xw[(size_t)i * F + lane] * d2;
        for (; j + 1 < end; j += 2) {
            int s0 = csr_src[j], s1 = csr_src[j + 1];
            float n0 = csr_nrm[j], n1 = csr_nrm[j + 1];
            float v0 = xw[(size_t)s0 * F + lane];
            float v1 = xw[(size_t)s1 * F + lane];
            a0 = fmaf(v0, n0, a0);
            a0 = fmaf(v1, n1, a0);
        }
        if (j < end) {
            int s0 = csr_src[j];
            float n0 = csr_nrm[j];
            a0 = fmaf(xw[(size_t)s0 * F + lane], n0, a0);
        }
        float o = a0 + bias[lane];
        if (RELU) o = fmaxf(o, 0.f);
        out[(size_t)i * F + lane] = o;
    }
}

extern "C" void kernel_launch(void* const* d_in, const int* in_sizes, int n_in,
                              void* d_out, int out_size, void* d_ws, size_t ws_size,
                              hipStream_t stream) {
    const float* x  = (const float*)d_in[0];
    const int*   ei = (const int*)d_in[1];
    const float* W1 = (const float*)d_in[2];
    const float* b1 = (const float*)d_in[3];
    const float* W2 = (const float*)d_in[4];
    const float* b2 = (const float*)d_in[5];
    const float* W3 = (const float*)d_in[6];
    const float* b3 = (const float*)d_in[7];
    float* out = (float*)d_out;

    int E = in_sizes[1] / 2;
    int n = in_sizes[0] / C_IN;
    const int* src = ei;
    const int* dst = ei + E;

    // workspace layout
    float* A       = (float*)d_ws;                   // [n*128] xw
    float* B       = A + (size_t)n * C_HID;          // [n*128] h
    float* dinv    = B + (size_t)n * C_HID;          // [n]
    float* csr_nrm = dinv + n;                       // [E]
    int*   degi    = (int*)(csr_nrm + E);            // [n]
    int*   cursor  = degi + n;                       // [n]
    int*   rowptr  = cursor + n;                     // [n+1]
    int*   partials= rowptr + n + 1;                 // [<=64]
    int*   csr_src = partials + 64;                  // [E]

    int nb = (n + SCAN_ELEMS - 1) / SCAN_ELEMS;

    // ---- CSR build (once; reused by all 3 layers) ----
    hipMemsetAsync(degi, 0, (size_t)n * sizeof(int), stream);
    hipMemsetAsync(cursor, 0, (size_t)n * sizeof(int), stream);
    count_deg_kernel<<<(E + 255) / 256, 256, 0, stream>>>(dst, E, degi);
    dinv_kernel<<<(n + 255) / 256, 256, 0, stream>>>(degi, dinv, n);
    scan1_kernel<<<nb, SCAN_T, 0, stream>>>(degi, n, rowptr, partials);
    scan2_kernel<<<1, 64, 0, stream>>>(partials, nb);
    scan3_kernel<<<(n + 255) / 256, 256, 0, stream>>>(rowptr, partials, n, E);
    fill_csr_kernel<<<(E + 255) / 256, 256, 0, stream>>>(src, dst, E, dinv, rowptr,
                                                         cursor, csr_src, csr_nrm);

    dim3 g128((n + 63) / 64, C_HID / 64);
    dim3 g64((n + 63) / 64, 1);
    int aggBlocks = (n + 3) / 4;

    // ---- layer 1 ----
    gemm_k128<C_HID><<<g128, 256, 0, stream>>>(x, W1, A, n);
    agg_kernel<C_HID, false><<<aggBlocks, 256, 0, stream>>>(rowptr, csr_src, csr_nrm,
                                                            A, dinv, b1, B, n);
    // ---- layer 2 ----
    gemm_k128<C_HID><<<g128, 256, 0, stream>>>(B, W2, A, n);
    agg_kernel<C_HID, false><<<aggBlocks, 256, 0, stream>>>(rowptr, csr_src, csr_nrm,
                                                            A, dinv, b2, B, n);
    // ---- layer 3 ----
    gemm_k128<C_OUT><<<g64, 256, 0, stream>>>(B, W3, A, n);
    agg_kernel<C_OUT, true><<<aggBlocks, 256, 0, stream>>>(rowptr, csr_src, csr_nrm,
                                                           A, dinv, b3, out, n);
}

// Round 3
// 407.238 us; speedup vs baseline: 8.9015x; 1.0777x over previous
//
#include <hip/hip_runtime.h>

// GCN 3-layer: N=50000, E=800000, dims 128->128->128->64, fp32.
// CSR (counting sort by dst) built once per launch; per layer:
//   gemm (LDS-tiled fp32) -> per-node wave gather-aggregate (fused self-loop,
//   bias, relu), neighbor loop unrolled x4 for memory-level parallelism.
// CSR entries packed int2{src, float_bits(norm)}. rowptr is consumed
// destructively by fill (atomicAdd on rowptr itself => shifted-by-one reads).

#define C_IN 128
#define C_HID 128
#define C_OUT 64
#define SCAN_T 256
#define SCAN_ELEMS (SCAN_T * 4)

// ---------------- CSR build ----------------

__global__ void count_deg_kernel(const int* __restrict__ dst, int E, int* __restrict__ degi) {
    int e = blockIdx.x * blockDim.x + threadIdx.x;
    if (e < E) atomicAdd(&degi[dst[e]], 1);
}

// pass 1: per-block (1024 elems) exclusive scan + block totals; also emits dinv.
__global__ void scan1_kernel(const int* __restrict__ degi, int n,
                             int* __restrict__ excl, int* __restrict__ partials,
                             float* __restrict__ dinv) {
    __shared__ int lds[SCAN_T];
    int tid = threadIdx.x;
    int base = blockIdx.x * SCAN_ELEMS + tid * 4;
    int a0 = (base + 0 < n) ? degi[base + 0] : 0;
    int a1 = (base + 1 < n) ? degi[base + 1] : 0;
    int a2 = (base + 2 < n) ? degi[base + 2] : 0;
    int a3 = (base + 3 < n) ? degi[base + 3] : 0;
    if (base + 0 < n) dinv[base + 0] = rsqrtf((float)a0 + 1.0f);
    if (base + 1 < n) dinv[base + 1] = rsqrtf((float)a1 + 1.0f);
    if (base + 2 < n) dinv[base + 2] = rsqrtf((float)a2 + 1.0f);
    if (base + 3 < n) dinv[base + 3] = rsqrtf((float)a3 + 1.0f);
    int t = a0 + a1 + a2 + a3;
    lds[tid] = t;
    __syncthreads();
    for (int off = 1; off < SCAN_T; off <<= 1) {
        int v = (tid >= off) ? lds[tid - off] : 0;
        __syncthreads();
        lds[tid] += v;
        __syncthreads();
    }
    int incl = lds[tid];
    int ex = incl - t;
    if (base + 0 < n) excl[base + 0] = ex;
    if (base + 1 < n) excl[base + 1] = ex + a0;
    if (base + 2 < n) excl[base + 2] = ex + a0 + a1;
    if (base + 3 < n) excl[base + 3] = ex + a0 + a1 + a2;
    if (tid == SCAN_T - 1) partials[blockIdx.x] = incl;
}

// pass 2: serial exclusive scan of ~49 block totals (negligible)
__global__ void scan2_kernel(int* __restrict__ partials, int nb) {
    if (threadIdx.x == 0 && blockIdx.x == 0) {
        int run = 0;
        for (int i = 0; i < nb; ++i) { int v = partials[i]; partials[i] = run; run += v; }
    }
}

// pass 3: add block offsets
__global__ void scan3_kernel(int* __restrict__ excl, const int* __restrict__ partials, int n) {
    int gid = blockIdx.x * blockDim.x + threadIdx.x;
    if (gid < n) excl[gid] += partials[gid / SCAN_ELEMS];
}

// fill: atomicAdd directly on rowptr (destructive). After this kernel,
// rowptr[i] == start of row i+1.  csr entry = {src, float_bits(norm)}.
__global__ void fill_csr_kernel(const int* __restrict__ src, const int* __restrict__ dst, int E,
                                const float* __restrict__ dinv, int* __restrict__ rowptr,
                                int2* __restrict__ csr) {
    int e = blockIdx.x * blockDim.x + threadIdx.x;
    if (e >= E) return;
    int s = src[e], d = dst[e];
    int pos = atomicAdd(&rowptr[d], 1);
    float nrm = dinv[s] * dinv[d];
    csr[pos] = make_int2(s, __float_as_int(nrm));
}

// ---------------- GEMM: X[n,128] @ W[128,FOUT] -> Y[n,FOUT] ----------------
template <int FOUT>
__global__ __launch_bounds__(256, 2) void gemm_k128(const float* __restrict__ X,
                                                    const float* __restrict__ W,
                                                    float* __restrict__ Y, int n) {
    constexpr int K = 128;
    constexpr int CT = 64;
    constexpr int MT = 64;
    constexpr int NQ = CT / 4;
    constexpr int RPT = 4;
    __shared__ float Ws[K][CT];
    __shared__ float Xs[MT][K + 4];

    int tid = threadIdx.x;
    int row0 = blockIdx.x * MT;
    int col0 = blockIdx.y * CT;

#pragma unroll
    for (int i = 0; i < (K * CT / 4) / 256; ++i) {
        int idx = tid + i * 256;
        int k = idx / (CT / 4);
        int c = idx % (CT / 4);
        *(float4*)&Ws[k][c * 4] = *(const float4*)(W + (size_t)k * FOUT + col0 + c * 4);
    }
#pragma unroll
    for (int i = 0; i < (MT * K / 4) / 256; ++i) {
        int idx = tid + i * 256;
        int r = idx / (K / 4);
        int c = idx % (K / 4);
        int gr = row0 + r;
        float4 v = (gr < n) ? *(const float4*)(X + (size_t)gr * K + c * 4)
                            : make_float4(0.f, 0.f, 0.f, 0.f);
        *(float4*)&Xs[r][c * 4] = v;
    }
    __syncthreads();

    int cq = tid % NQ;
    int rg = tid / NQ;
    float acc[RPT][4] = {};

    for (int k4 = 0; k4 < K / 4; ++k4) {
        float xa[RPT][4];
#pragma unroll
        for (int r = 0; r < RPT; ++r) {
            float4 t = *(float4*)&Xs[rg * RPT + r][k4 * 4];
            xa[r][0] = t.x; xa[r][1] = t.y; xa[r][2] = t.z; xa[r][3] = t.w;
        }
#pragma unroll
        for (int kk = 0; kk < 4; ++kk) {
            float4 w = *(float4*)&Ws[k4 * 4 + kk][cq * 4];
#pragma unroll
            for (int r = 0; r < RPT; ++r) {
                acc[r][0] = fmaf(xa[r][kk], w.x, acc[r][0]);
                acc[r][1] = fmaf(xa[r][kk], w.y, acc[r][1]);
                acc[r][2] = fmaf(xa[r][kk], w.z, acc[r][2]);
                acc[r][3] = fmaf(xa[r][kk], w.w, acc[r][3]);
            }
        }
    }
#pragma unroll
    for (int r = 0; r < RPT; ++r) {
        int gr = row0 + rg * RPT + r;
        if (gr < n)
            *(float4*)(Y + (size_t)gr * FOUT + col0 + cq * 4) =
                make_float4(acc[r][0], acc[r][1], acc[r][2], acc[r][3]);
    }
}

// ------- fused aggregate: out = sum_j nrm*xw[src] + xw*dinv^2 + b [+relu] -------
// One wave per node; neighbor loop unrolled x4 (4 independent gathers in flight).
// rowptr is the post-fill shifted array: row i spans [i==0?0:rowptr[i-1], rowptr[i]).
template <int F, bool RELU>
__global__ __launch_bounds__(256) void agg_kernel(const int* __restrict__ rowptr,
                                                  const int2* __restrict__ csr,
                                                  const float* __restrict__ xw,
                                                  const float* __restrict__ dinv,
                                                  const float* __restrict__ bias,
                                                  float* __restrict__ out, int n) {
    int wave = threadIdx.x >> 6;
    int lane = threadIdx.x & 63;
    int i = blockIdx.x * 4 + wave;
    if (i >= n) return;
    float di = dinv[i];
    float d2 = di * di;
    int j = (i == 0) ? 0 : rowptr[i - 1];
    int end = rowptr[i];

    if constexpr (F == 128) {
        float2 x0 = ((const float2*)(xw + (size_t)i * F))[lane];
        float2 a0, a1, a2, a3;
        a0.x = x0.x * d2; a0.y = x0.y * d2;
        a1.x = a1.y = a2.x = a2.y = a3.x = a3.y = 0.f;
        for (; j + 4 <= end; j += 4) {
            int2 e0 = csr[j], e1 = csr[j + 1], e2 = csr[j + 2], e3 = csr[j + 3];
            float2 v0 = ((const float2*)(xw + (size_t)e0.x * F))[lane];
            float2 v1 = ((const float2*)(xw + (size_t)e1.x * F))[lane];
            float2 v2 = ((const float2*)(xw + (size_t)e2.x * F))[lane];
            float2 v3 = ((const float2*)(xw + (size_t)e3.x * F))[lane];
            float n0 = __int_as_float(e0.y), n1 = __int_as_float(e1.y);
            float n2 = __int_as_float(e2.y), n3 = __int_as_float(e3.y);
            a0.x = fmaf(v0.x, n0, a0.x); a0.y = fmaf(v0.y, n0, a0.y);
            a1.x = fmaf(v1.x, n1, a1.x); a1.y = fmaf(v1.y, n1, a1.y);
            a2.x = fmaf(v2.x, n2, a2.x); a2.y = fmaf(v2.y, n2, a2.y);
            a3.x = fmaf(v3.x, n3, a3.x); a3.y = fmaf(v3.y, n3, a3.y);
        }
        for (; j < end; ++j) {
            int2 e0 = csr[j];
            float2 v0 = ((const float2*)(xw + (size_t)e0.x * F))[lane];
            float n0 = __int_as_float(e0.y);
            a0.x = fmaf(v0.x, n0, a0.x); a0.y = fmaf(v0.y, n0, a0.y);
        }
        float2 bv = ((const float2*)bias)[lane];
        float2 o;
        o.x = (a0.x + a1.x) + (a2.x + a3.x) + bv.x;
        o.y = (a0.y + a1.y) + (a2.y + a3.y) + bv.y;
        if (RELU) { o.x = fmaxf(o.x, 0.f); o.y = fmaxf(o.y, 0.f); }
        ((float2*)(out + (size_t)i * F))[lane] = o;
    } else {  // F == 64, one float per lane
        float a0 = xw[(size_t)i * F + lane] * d2;
        float a1 = 0.f, a2 = 0.f, a3 = 0.f;
        for (; j + 4 <= end; j += 4) {
            int2 e0 = csr[j], e1 = csr[j + 1], e2 = csr[j + 2], e3 = csr[j + 3];
            float v0 = xw[(size_t)e0.x * F + lane];
            float v1 = xw[(size_t)e1.x * F + lane];
            float v2 = xw[(size_t)e2.x * F + lane];
            float v3 = xw[(size_t)e3.x * F + lane];
            a0 = fmaf(v0, __int_as_float(e0.y), a0);
            a1 = fmaf(v1, __int_as_float(e1.y), a1);
            a2 = fmaf(v2, __int_as_float(e2.y), a2);
            a3 = fmaf(v3, __int_as_float(e3.y), a3);
        }
        for (; j < end; ++j) {
            int2 e0 = csr[j];
            a0 = fmaf(xw[(size_t)e0.x * F + lane], __int_as_float(e0.y), a0);
        }
        float o = (a0 + a1) + (a2 + a3) + bias[lane];
        if (RELU) o = fmaxf(o, 0.f);
        out[(size_t)i * F + lane] = o;
    }
}

extern "C" void kernel_launch(void* const* d_in, const int* in_sizes, int n_in,
                              void* d_out, int out_size, void* d_ws, size_t ws_size,
                              hipStream_t stream) {
    const float* x  = (const float*)d_in[0];
    const int*   ei = (const int*)d_in[1];
    const float* W1 = (const float*)d_in[2];
    const float* b1 = (const float*)d_in[3];
    const float* W2 = (const float*)d_in[4];
    const float* b2 = (const float*)d_in[5];
    const float* W3 = (const float*)d_in[6];
    const float* b3 = (const float*)d_in[7];
    float* out = (float*)d_out;

    int E = in_sizes[1] / 2;
    int n = in_sizes[0] / C_IN;
    const int* src = ei;
    const int* dst = ei + E;

    // workspace layout (A,B are n*128 floats -> csr is 8B-aligned)
    float* A        = (float*)d_ws;                  // [n*128] xw
    float* B        = A + (size_t)n * C_HID;         // [n*128] h
    int2*  csr      = (int2*)(B + (size_t)n * C_HID);// [E]
    float* dinv     = (float*)(csr + E);             // [n]
    int*   degi     = (int*)(dinv + n);              // [n]
    int*   rowptr   = degi + n;                      // [n+1]
    int*   partials = rowptr + n + 1;                // [<=64]

    int nb = (n + SCAN_ELEMS - 1) / SCAN_ELEMS;

    // ---- CSR build (once; reused by all 3 layers) ----
    hipMemsetAsync(degi, 0, (size_t)n * sizeof(int), stream);
    count_deg_kernel<<<(E + 255) / 256, 256, 0, stream>>>(dst, E, degi);
    scan1_kernel<<<nb, SCAN_T, 0, stream>>>(degi, n, rowptr, partials, dinv);
    scan2_kernel<<<1, 64, 0, stream>>>(partials, nb);
    scan3_kernel<<<(n + 255) / 256, 256, 0, stream>>>(rowptr, partials, n);
    fill_csr_kernel<<<(E + 255) / 256, 256, 0, stream>>>(src, dst, E, dinv, rowptr, csr);

    dim3 g128((n + 63) / 64, C_HID / 64);
    dim3 g64((n + 63) / 64, 1);
    int aggBlocks = (n + 3) / 4;

    // ---- layer 1 ----
    gemm_k128<C_HID><<<g128, 256, 0, stream>>>(x, W1, A, n);
    agg_kernel<C_HID, false><<<aggBlocks, 256, 0, stream>>>(rowptr, csr, A, dinv, b1, B, n);
    // ---- layer 2 ----
    gemm_k128<C_HID><<<g128, 256, 0, stream>>>(B, W2, A, n);
    agg_kernel<C_HID, false><<<aggBlocks, 256, 0, stream>>>(rowptr, csr, A, dinv, b2, B, n);
    // ---- layer 3 ----
    gemm_k128<C_OUT><<<g64, 256, 0, stream>>>(B, W3, A, n);
    agg_kernel<C_OUT, true><<<aggBlocks, 256, 0, stream>>>(rowptr, csr, A, dinv, b3, out, n);
}

// Round 4
// 394.226 us; speedup vs baseline: 9.1953x; 1.0330x over previous
//
#include <hip/hip_runtime.h>

// GCN 3-layer: N=50000, E=800000, dims 128->128->128->64, fp32.
// CSR (counting sort by dst) built once per launch; per layer:
//   gemm (LDS-tiled fp32) -> per-node wave gather-aggregate.
// Aggregate: one wave per node, node index readfirstlane'd so csr/rowptr
// reads go scalar (s_load) and up to 16 row-gathers are in flight per wave
// (graded 16/8/4 batches + clamp-masked tail). Self-loop, bias, relu fused.

#define C_IN 128
#define C_HID 128
#define C_OUT 64
#define SCAN_T 256
#define SCAN_ELEMS (SCAN_T * 4)

// ---------------- CSR build ----------------

__global__ void count_deg_kernel(const int* __restrict__ dst, int E, int* __restrict__ degi) {
    int e = blockIdx.x * blockDim.x + threadIdx.x;
    if (e < E) atomicAdd(&degi[dst[e]], 1);
}

// pass 1: per-block (1024 elems) exclusive scan + block totals; also emits dinv.
__global__ void scan1_kernel(const int* __restrict__ degi, int n,
                             int* __restrict__ excl, int* __restrict__ partials,
                             float* __restrict__ dinv) {
    __shared__ int lds[SCAN_T];
    int tid = threadIdx.x;
    int base = blockIdx.x * SCAN_ELEMS + tid * 4;
    int a0 = (base + 0 < n) ? degi[base + 0] : 0;
    int a1 = (base + 1 < n) ? degi[base + 1] : 0;
    int a2 = (base + 2 < n) ? degi[base + 2] : 0;
    int a3 = (base + 3 < n) ? degi[base + 3] : 0;
    if (base + 0 < n) dinv[base + 0] = rsqrtf((float)a0 + 1.0f);
    if (base + 1 < n) dinv[base + 1] = rsqrtf((float)a1 + 1.0f);
    if (base + 2 < n) dinv[base + 2] = rsqrtf((float)a2 + 1.0f);
    if (base + 3 < n) dinv[base + 3] = rsqrtf((float)a3 + 1.0f);
    int t = a0 + a1 + a2 + a3;
    lds[tid] = t;
    __syncthreads();
    for (int off = 1; off < SCAN_T; off <<= 1) {
        int v = (tid >= off) ? lds[tid - off] : 0;
        __syncthreads();
        lds[tid] += v;
        __syncthreads();
    }
    int incl = lds[tid];
    int ex = incl - t;
    if (base + 0 < n) excl[base + 0] = ex;
    if (base + 1 < n) excl[base + 1] = ex + a0;
    if (base + 2 < n) excl[base + 2] = ex + a0 + a1;
    if (base + 3 < n) excl[base + 3] = ex + a0 + a1 + a2;
    if (tid == SCAN_T - 1) partials[blockIdx.x] = incl;
}

__global__ void scan2_kernel(int* __restrict__ partials, int nb) {
    if (threadIdx.x == 0 && blockIdx.x == 0) {
        int run = 0;
        for (int i = 0; i < nb; ++i) { int v = partials[i]; partials[i] = run; run += v; }
    }
}

__global__ void scan3_kernel(int* __restrict__ excl, const int* __restrict__ partials, int n) {
    int gid = blockIdx.x * blockDim.x + threadIdx.x;
    if (gid < n) excl[gid] += partials[gid / SCAN_ELEMS];
}

// fill: atomicAdd directly on rowptr (destructive). After this kernel,
// rowptr[i] == start of row i+1.  csr entry = {src, float_bits(norm)}.
__global__ void fill_csr_kernel(const int* __restrict__ src, const int* __restrict__ dst, int E,
                                const float* __restrict__ dinv, int* __restrict__ rowptr,
                                int2* __restrict__ csr) {
    int e = blockIdx.x * blockDim.x + threadIdx.x;
    if (e >= E) return;
    int s = src[e], d = dst[e];
    int pos = atomicAdd(&rowptr[d], 1);
    float nrm = dinv[s] * dinv[d];
    csr[pos] = make_int2(s, __float_as_int(nrm));
}

// ---------------- GEMM: X[n,128] @ W[128,FOUT] -> Y[n,FOUT] ----------------
template <int FOUT>
__global__ __launch_bounds__(256, 2) void gemm_k128(const float* __restrict__ X,
                                                    const float* __restrict__ W,
                                                    float* __restrict__ Y, int n) {
    constexpr int K = 128;
    constexpr int CT = 64;
    constexpr int MT = 64;
    constexpr int NQ = CT / 4;
    constexpr int RPT = 4;
    __shared__ float Ws[K][CT];
    __shared__ float Xs[MT][K + 4];

    int tid = threadIdx.x;
    int row0 = blockIdx.x * MT;
    int col0 = blockIdx.y * CT;

#pragma unroll
    for (int i = 0; i < (K * CT / 4) / 256; ++i) {
        int idx = tid + i * 256;
        int k = idx / (CT / 4);
        int c = idx % (CT / 4);
        *(float4*)&Ws[k][c * 4] = *(const float4*)(W + (size_t)k * FOUT + col0 + c * 4);
    }
#pragma unroll
    for (int i = 0; i < (MT * K / 4) / 256; ++i) {
        int idx = tid + i * 256;
        int r = idx / (K / 4);
        int c = idx % (K / 4);
        int gr = row0 + r;
        float4 v = (gr < n) ? *(const float4*)(X + (size_t)gr * K + c * 4)
                            : make_float4(0.f, 0.f, 0.f, 0.f);
        *(float4*)&Xs[r][c * 4] = v;
    }
    __syncthreads();

    int cq = tid % NQ;
    int rg = tid / NQ;
    float acc[RPT][4] = {};

    for (int k4 = 0; k4 < K / 4; ++k4) {
        float xa[RPT][4];
#pragma unroll
        for (int r = 0; r < RPT; ++r) {
            float4 t = *(float4*)&Xs[rg * RPT + r][k4 * 4];
            xa[r][0] = t.x; xa[r][1] = t.y; xa[r][2] = t.z; xa[r][3] = t.w;
        }
#pragma unroll
        for (int kk = 0; kk < 4; ++kk) {
            float4 w = *(float4*)&Ws[k4 * 4 + kk][cq * 4];
#pragma unroll
            for (int r = 0; r < RPT; ++r) {
                acc[r][0] = fmaf(xa[r][kk], w.x, acc[r][0]);
                acc[r][1] = fmaf(xa[r][kk], w.y, acc[r][1]);
                acc[r][2] = fmaf(xa[r][kk], w.z, acc[r][2]);
                acc[r][3] = fmaf(xa[r][kk], w.w, acc[r][3]);
            }
        }
    }
#pragma unroll
    for (int r = 0; r < RPT; ++r) {
        int gr = row0 + rg * RPT + r;
        if (gr < n)
            *(float4*)(Y + (size_t)gr * FOUT + col0 + cq * 4) =
                make_float4(acc[r][0], acc[r][1], acc[r][2], acc[r][3]);
    }
}

// ---------------- aggregate helpers ----------------
// One batch of NB edges: NB wave-uniform csr reads -> NB independent row
// gathers -> FMA into acc[0..3] (unroll-constant indexing).
// MASK: clamp edge index into the row and zero the weight for k >= rem.

template <int NB, bool MASK>
__device__ __forceinline__ void batch_f128(const int2* __restrict__ csr, int j, int rem,
                                           const float* __restrict__ xw, int lane,
                                           float2* acc) {
    int s[NB];
    float nm[NB];
#pragma unroll
    for (int k = 0; k < NB; ++k) {
        int jj = MASK ? (j + ((k < rem) ? k : 0)) : (j + k);
        int2 e = csr[jj];
        s[k] = e.x;
        nm[k] = (!MASK || (k < rem)) ? __int_as_float(e.y) : 0.0f;
    }
    float2 v[NB];
#pragma unroll
    for (int k = 0; k < NB; ++k)
        v[k] = ((const float2*)(xw + (size_t)s[k] * 128))[lane];
#pragma unroll
    for (int k = 0; k < NB; ++k) {
        acc[k & 3].x = fmaf(v[k].x, nm[k], acc[k & 3].x);
        acc[k & 3].y = fmaf(v[k].y, nm[k], acc[k & 3].y);
    }
}

template <int NB, bool MASK>
__device__ __forceinline__ void batch_f64(const int2* __restrict__ csr, int j, int rem,
                                          const float* __restrict__ xw, int lane,
                                          float* acc) {
    int s[NB];
    float nm[NB];
#pragma unroll
    for (int k = 0; k < NB; ++k) {
        int jj = MASK ? (j + ((k < rem) ? k : 0)) : (j + k);
        int2 e = csr[jj];
        s[k] = e.x;
        nm[k] = (!MASK || (k < rem)) ? __int_as_float(e.y) : 0.0f;
    }
    float v[NB];
#pragma unroll
    for (int k = 0; k < NB; ++k)
        v[k] = xw[(size_t)s[k] * 64 + lane];
#pragma unroll
    for (int k = 0; k < NB; ++k)
        acc[k & 3] = fmaf(v[k], nm[k], acc[k & 3]);
}

// ------- fused aggregate: out = sum_j nrm*xw[src] + xw*dinv^2 + b [+relu] -------
// rowptr is the post-fill shifted array: row i spans [i==0?0:rowptr[i-1], rowptr[i]).
template <int F, bool RELU>
__global__ __launch_bounds__(256) void agg_kernel(const int* __restrict__ rowptr,
                                                  const int2* __restrict__ csr,
                                                  const float* __restrict__ xw,
                                                  const float* __restrict__ dinv,
                                                  const float* __restrict__ bias,
                                                  float* __restrict__ out, int n) {
    int wave = threadIdx.x >> 6;
    int lane = threadIdx.x & 63;
    int i0 = blockIdx.x * 4 + wave;
    if (i0 >= n) return;
    // node index is wave-uniform: pin it to SGPR so rowptr/csr reads go scalar.
    int i = __builtin_amdgcn_readfirstlane(i0);
    float di = dinv[i];
    float d2 = di * di;
    int j = (i == 0) ? 0 : rowptr[i - 1];
    int end = rowptr[i];
    j = __builtin_amdgcn_readfirstlane(j);
    end = __builtin_amdgcn_readfirstlane(end);

    if constexpr (F == 128) {
        float2 x0 = ((const float2*)(xw + (size_t)i * F))[lane];
        float2 acc[4];
        acc[0].x = x0.x * d2; acc[0].y = x0.y * d2;
        acc[1] = acc[2] = acc[3] = make_float2(0.f, 0.f);

        for (; j + 16 <= end; j += 16) batch_f128<16, false>(csr, j, 0, xw, lane, acc);
        if (j + 8 <= end) { batch_f128<8, false>(csr, j, 0, xw, lane, acc); j += 8; }
        if (j + 4 <= end) { batch_f128<4, false>(csr, j, 0, xw, lane, acc); j += 4; }
        int rem = end - j;
        if (rem > 0) batch_f128<4, true>(csr, j, rem, xw, lane, acc);

        float2 bv = ((const float2*)bias)[lane];
        float2 o;
        o.x = (acc[0].x + acc[1].x) + (acc[2].x + acc[3].x) + bv.x;
        o.y = (acc[0].y + acc[1].y) + (acc[2].y + acc[3].y) + bv.y;
        if (RELU) { o.x = fmaxf(o.x, 0.f); o.y = fmaxf(o.y, 0.f); }
        ((float2*)(out + (size_t)i * F))[lane] = o;
    } else {  // F == 64
        float acc[4];
        acc[0] = xw[(size_t)i * F + lane] * d2;
        acc[1] = acc[2] = acc[3] = 0.f;

        for (; j + 16 <= end; j += 16) batch_f64<16, false>(csr, j, 0, xw, lane, acc);
        if (j + 8 <= end) { batch_f64<8, false>(csr, j, 0, xw, lane, acc); j += 8; }
        if (j + 4 <= end) { batch_f64<4, false>(csr, j, 0, xw, lane, acc); j += 4; }
        int rem = end - j;
        if (rem > 0) batch_f64<4, true>(csr, j, rem, xw, lane, acc);

        float o = (acc[0] + acc[1]) + (acc[2] + acc[3]) + bias[lane];
        if (RELU) o = fmaxf(o, 0.f);
        out[(size_t)i * F + lane] = o;
    }
}

extern "C" void kernel_launch(void* const* d_in, const int* in_sizes, int n_in,
                              void* d_out, int out_size, void* d_ws, size_t ws_size,
                              hipStream_t stream) {
    const float* x  = (const float*)d_in[0];
    const int*   ei = (const int*)d_in[1];
    const float* W1 = (const float*)d_in[2];
    const float* b1 = (const float*)d_in[3];
    const float* W2 = (const float*)d_in[4];
    const float* b2 = (const float*)d_in[5];
    const float* W3 = (const float*)d_in[6];
    const float* b3 = (const float*)d_in[7];
    float* out = (float*)d_out;

    int E = in_sizes[1] / 2;
    int n = in_sizes[0] / C_IN;
    const int* src = ei;
    const int* dst = ei + E;

    // workspace layout (A,B are n*128 floats -> csr is 8B-aligned)
    float* A        = (float*)d_ws;                  // [n*128] xw
    float* B        = A + (size_t)n * C_HID;         // [n*128] h
    int2*  csr      = (int2*)(B + (size_t)n * C_HID);// [E]
    float* dinv     = (float*)(csr + E);             // [n]
    int*   degi     = (int*)(dinv + n);              // [n]
    int*   rowptr   = degi + n;                      // [n+1]
    int*   partials = rowptr + n + 1;                // [<=64]

    int nb = (n + SCAN_ELEMS - 1) / SCAN_ELEMS;

    // ---- CSR build (once; reused by all 3 layers) ----
    hipMemsetAsync(degi, 0, (size_t)n * sizeof(int), stream);
    count_deg_kernel<<<(E + 255) / 256, 256, 0, stream>>>(dst, E, degi);
    scan1_kernel<<<nb, SCAN_T, 0, stream>>>(degi, n, rowptr, partials, dinv);
    scan2_kernel<<<1, 64, 0, stream>>>(partials, nb);
    scan3_kernel<<<(n + 255) / 256, 256, 0, stream>>>(rowptr, partials, n);
    fill_csr_kernel<<<(E + 255) / 256, 256, 0, stream>>>(src, dst, E, dinv, rowptr, csr);

    dim3 g128((n + 63) / 64, C_HID / 64);
    dim3 g64((n + 63) / 64, 1);
    int aggBlocks = (n + 3) / 4;

    // ---- layer 1 ----
    gemm_k128<C_HID><<<g128, 256, 0, stream>>>(x, W1, A, n);
    agg_kernel<C_HID, false><<<aggBlocks, 256, 0, stream>>>(rowptr, csr, A, dinv, b1, B, n);
    // ---- layer 2 ----
    gemm_k128<C_HID><<<g128, 256, 0, stream>>>(B, W2, A, n);
    agg_kernel<C_HID, false><<<aggBlocks, 256, 0, stream>>>(rowptr, csr, A, dinv, b2, B, n);
    // ---- layer 3 ----
    gemm_k128<C_OUT><<<g64, 256, 0, stream>>>(B, W3, A, n);
    agg_kernel<C_OUT, true><<<aggBlocks, 256, 0, stream>>>(rowptr, csr, A, dinv, b3, out, n);
}